// Round 1
// baseline (482.700 us; speedup 1.0000x reference)
//
#include <hip/hip_runtime.h>
#include <hip/hip_bf16.h>
#include <cstdint>

#define TOKENS 2048
#define Dm 1024
#define Fm 4096
#define Em 8
#define ROWCAP 5120

typedef short s16x8 __attribute__((ext_vector_type(8)));
typedef float f32x4 __attribute__((ext_vector_type(4)));

#define GLOAD16(g, l) __builtin_amdgcn_global_load_lds(                     \
    (const __attribute__((address_space(1))) void*)(g),                     \
    (__attribute__((address_space(3))) void*)(l), 16, 0, 0)

__device__ __forceinline__ ushort f2bf(float f) {
  union { float f; uint32_t u; } v; v.f = f;
  uint32_t r = v.u + 0x7fffu + ((v.u >> 16) & 1u);
  return (ushort)(r >> 16);
}

// ---------------- x -> bf16 ----------------
__global__ void cvt_x(const float* __restrict__ x, ushort* __restrict__ xb) {
  int i = blockIdx.x * 256 + threadIdx.x;           // 4 elems per thread
  float4 v = ((const float4*)x)[i];
  ushort4 o;
  o.x = f2bf(v.x); o.y = f2bf(v.y); o.z = f2bf(v.z); o.w = f2bf(v.w);
  ((ushort4*)xb)[i] = o;
}

// ------------- transpose+convert: in[e][r][c] f32 -> out[e][c][r] bf16 -------------
__global__ void transcvt(const float* __restrict__ in, ushort* __restrict__ out,
                         int R, int C) {
  __shared__ float tile[32][33];
  int e = blockIdx.z;
  const float* src = in + (size_t)e * R * C;
  ushort* dst = out + (size_t)e * R * C;
  int c0 = blockIdx.x * 32, r0 = blockIdx.y * 32;
  int lr = threadIdx.x >> 5, lc = threadIdx.x & 31; // 8 rows per pass
#pragma unroll
  for (int p = 0; p < 4; ++p) {
    int r = r0 + p * 8 + lr;
    tile[p * 8 + lr][lc] = src[(size_t)r * C + c0 + lc];
  }
  __syncthreads();
#pragma unroll
  for (int p = 0; p < 4; ++p) {
    int c = c0 + p * 8 + lr;
    dst[(size_t)c * R + r0 + lc] = f2bf(tile[lc][p * 8 + lr]);
  }
}

// ---------------- router: logits, top-2, softmax ----------------
__global__ void router(const float* __restrict__ x, const float* __restrict__ Wr,
                       const float* __restrict__ br, float* __restrict__ probs,
                       int* __restrict__ e_sel, float* __restrict__ w_sel) {
  int t = blockIdx.x;
  const float* xr = x + (size_t)t * Dm;
  float acc[Em];
#pragma unroll
  for (int e = 0; e < Em; ++e) acc[e] = 0.f;
  for (int d = threadIdx.x; d < Dm; d += 256) {
    float xv = xr[d];
    const float* wr = Wr + (size_t)d * Em;
#pragma unroll
    for (int e = 0; e < Em; ++e) acc[e] += xv * wr[e];
  }
#pragma unroll
  for (int off = 32; off >= 1; off >>= 1)
#pragma unroll
    for (int e = 0; e < Em; ++e) acc[e] += __shfl_down(acc[e], off);
  __shared__ float red[4][Em];
  int lane = threadIdx.x & 63, wid = threadIdx.x >> 6;
  if (lane == 0)
#pragma unroll
    for (int e = 0; e < Em; ++e) red[wid][e] = acc[e];
  __syncthreads();
  if (threadIdx.x == 0) {
    float lg[Em];
#pragma unroll
    for (int e = 0; e < Em; ++e)
      lg[e] = red[0][e] + red[1][e] + red[2][e] + red[3][e] + br[e];
    int i0 = 0;
    for (int e = 1; e < Em; ++e) if (lg[e] > lg[i0]) i0 = e;
    int i1 = -1;
    for (int e = 0; e < Em; ++e) {
      if (e == i0) continue;
      if (i1 < 0 || lg[e] > lg[i1]) i1 = e;
    }
    float d = lg[i1] - lg[i0];
    float tt = __expf(d) * 0.f + expf(d);
    float inv = 1.f / (1.f + tt);
    float p0 = inv, p1 = tt * inv;
    probs[t * 2] = p0; probs[t * 2 + 1] = p1;
    e_sel[t * 2] = i0; e_sel[t * 2 + 1] = i1;
    w_sel[t * 2] = p0; w_sel[t * 2 + 1] = p1;
  }
}

// ---------------- stable per-expert list build (1 block, 256 thr) ----------------
__global__ void build_lists(const int* __restrict__ e_sel, const float* __restrict__ w_sel,
                            int* __restrict__ tok_of_row, float* __restrict__ w_of_row,
                            int* __restrict__ base, int* __restrict__ npad,
                            int* __restrict__ ncnt) {
  __shared__ int cnt[Em], run[Em], sbase[Em];
  __shared__ int wsum[4][Em];
  int tid = threadIdx.x, lane = tid & 63, wid = tid >> 6;
  if (tid < Em) { cnt[tid] = 0; run[tid] = 0; }
  __syncthreads();
  for (int t = tid; t < TOKENS; t += 256) {
    atomicAdd(&cnt[e_sel[2 * t]], 1);
    atomicAdd(&cnt[e_sel[2 * t + 1]], 1);
  }
  __syncthreads();
  if (tid == 0) {
    int b = 0;
    for (int e = 0; e < Em; ++e) {
      base[e] = b; sbase[e] = b;
      int n = cnt[e]; ncnt[e] = n;
      int p = (n + 127) & ~127;
      npad[e] = p; b += p;
    }
  }
  __syncthreads();
  for (int c = 0; c < TOKENS / 256; ++c) {
    int t = c * 256 + tid;
    int e0 = e_sel[2 * t], e1 = e_sel[2 * t + 1];
    unsigned long long mm[Em];
#pragma unroll
    for (int e = 0; e < Em; ++e) {
      unsigned long long m0 = __ballot(e0 == e);
      unsigned long long m1 = __ballot(e1 == e);
      mm[e] = m0 | m1;
      if (lane == 0) wsum[wid][e] = __popcll(mm[e]);
    }
    __syncthreads();
    unsigned long long below = (1ull << lane) - 1ull;
    {
      int e = e0;
      int p = __popcll(mm[e] & below);
      int pre = 0;
      for (int w = 0; w < wid; ++w) pre += wsum[w][e];
      int row = sbase[e] + run[e] + pre + p;
      tok_of_row[row] = t; w_of_row[row] = w_sel[2 * t];
    }
    {
      int e = e1;
      int p = __popcll(mm[e] & below);
      int pre = 0;
      for (int w = 0; w < wid; ++w) pre += wsum[w][e];
      int row = sbase[e] + run[e] + pre + p;
      tok_of_row[row] = t; w_of_row[row] = w_sel[2 * t + 1];
    }
    __syncthreads();
    if (tid < Em) {
      int s = 0;
      for (int w = 0; w < 4; ++w) s += wsum[w][tid];
      run[tid] += s;
    }
    __syncthreads();
  }
  // pad fill
  for (int e = 0; e < Em; ++e) {
    int n = cnt[e];
    int p = (n + 127) & ~127;
    for (int i = n + tid; i < p; i += 256) {
      tok_of_row[sbase[e] + i] = -1;
      w_of_row[sbase[e] + i] = 0.f;
    }
  }
}

// ---------------- out init: weighted b2 ----------------
__global__ void out_init(const int* __restrict__ e_sel, const float* __restrict__ w_sel,
                         const float* __restrict__ b2, float* __restrict__ out) {
  int t = blockIdx.x;
  int e0 = e_sel[2 * t], e1 = e_sel[2 * t + 1];
  float w0 = w_sel[2 * t], w1 = w_sel[2 * t + 1];
  const float4* p0 = (const float4*)(b2 + (size_t)e0 * Dm);
  const float4* p1 = (const float4*)(b2 + (size_t)e1 * Dm);
  float4* o = (float4*)(out + (size_t)t * Dm);
  for (int i = threadIdx.x; i < Dm / 4; i += 256) {
    float4 a = p0[i], b = p1[i];
    float4 r;
    r.x = w0 * a.x + w1 * b.x; r.y = w0 * a.y + w1 * b.y;
    r.z = w0 * a.z + w1 * b.z; r.w = w0 * a.w + w1 * b.w;
    o[i] = r;
  }
}

// ---------------- GEMM1: H = gelu(Xg @ W1T^T + b1), bf16 out ----------------
__global__ __launch_bounds__(256) void gemm1(
    const ushort* __restrict__ xb, const ushort* __restrict__ bmat,
    const float* __restrict__ b1, ushort* __restrict__ H,
    const int* __restrict__ tok_of_row, const int* __restrict__ base,
    const int* __restrict__ npad) {
  int e = blockIdx.x >> 4, rt = blockIdx.x & 15;
  int np = npad[e];
  if (rt * 128 >= np) return;
  int row0 = base[e] + rt * 128;
  int n0 = blockIdx.y * 128;
  __shared__ ushort As[128 * 32];
  __shared__ ushort Bs[128 * 32];
  __shared__ int toks[128];
  int tid = threadIdx.x, lane = tid & 63, wid = tid >> 6;
  if (tid < 128) toks[tid] = tok_of_row[row0 + tid];
  __syncthreads();
  int arow = tid >> 2, asub = tid & 3;
  int t0 = toks[arow];      if (t0 < 0) t0 = 0;
  int t1 = toks[64 + arow]; if (t1 < 0) t1 = 0;
  const ushort* sA0 = xb + (size_t)t0 * Dm + asub * 8;
  const ushort* sA1 = xb + (size_t)t1 * Dm + asub * 8;
  const ushort* sB0 = bmat + ((size_t)e * Fm + n0 + arow) * Dm + asub * 8;
  const ushort* sB1 = sB0 + (size_t)64 * Dm;
  char* ldA0 = (char*)As + wid * 1024;
  char* ldA1 = (char*)As + 4096 + wid * 1024;
  char* ldB0 = (char*)Bs + wid * 1024;
  char* ldB1 = (char*)Bs + 4096 + wid * 1024;
  int wr = wid >> 1, wc = wid & 1;
  const ushort* aB = As + ((size_t)(wr * 64 + (lane & 15)) * 32) + (lane >> 4) * 8;
  const ushort* bB = Bs + ((size_t)(wc * 64 + (lane & 15)) * 32) + (lane >> 4) * 8;
  f32x4 acc[4][4] = {};
  for (int kt = 0; kt < Dm / 32; ++kt) {
    GLOAD16(sA0, ldA0);
    GLOAD16(sA1, ldA1);
    GLOAD16(sB0, ldB0);
    GLOAD16(sB1, ldB1);
    sA0 += 32; sA1 += 32; sB0 += 32; sB1 += 32;
    __syncthreads();
    s16x8 av[4], bv[4];
#pragma unroll
    for (int m = 0; m < 4; ++m) av[m] = *(const s16x8*)(aB + m * 512);
#pragma unroll
    for (int n = 0; n < 4; ++n) bv[n] = *(const s16x8*)(bB + n * 512);
#pragma unroll
    for (int m = 0; m < 4; ++m)
#pragma unroll
      for (int n = 0; n < 4; ++n)
        acc[m][n] = __builtin_amdgcn_mfma_f32_16x16x32_bf16(av[m], bv[n], acc[m][n], 0, 0, 0);
    __syncthreads();
  }
  int rb = wr * 64 + ((lane >> 4) << 2);
  int cb = n0 + wc * 64 + (lane & 15);
#pragma unroll
  for (int n = 0; n < 4; ++n) {
    int col = cb + n * 16;
    float bias = b1[e * Fm + col];
#pragma unroll
    for (int m = 0; m < 4; ++m) {
      int r = row0 + rb + m * 16;
#pragma unroll
      for (int j = 0; j < 4; ++j) {
        float v = acc[m][n][j] + bias;
        float g = 0.5f * v * (1.f + erff(v * 0.70710678118654752f));
        H[(size_t)(r + j) * Fm + col] = f2bf(g);
      }
    }
  }
}

// ---------------- GEMM2: out[tok] += w * (H @ W2T^T) ----------------
__global__ __launch_bounds__(256) void gemm2(
    const ushort* __restrict__ H, const ushort* __restrict__ bmat,
    const int* __restrict__ tok_of_row, const float* __restrict__ w_of_row,
    const int* __restrict__ base, const int* __restrict__ npad,
    float* __restrict__ out) {
  int e = blockIdx.x >> 4, rt = blockIdx.x & 15;
  int np = npad[e];
  if (rt * 128 >= np) return;
  int row0 = base[e] + rt * 128;
  int n0 = blockIdx.y * 128;
  __shared__ ushort As[128 * 32];
  __shared__ ushort Bs[128 * 32];
  __shared__ int toks[128];
  __shared__ float wts[128];
  int tid = threadIdx.x, lane = tid & 63, wid = tid >> 6;
  if (tid < 128) {
    toks[tid] = tok_of_row[row0 + tid];
    wts[tid] = w_of_row[row0 + tid];
  }
  __syncthreads();
  int arow = tid >> 2, asub = tid & 3;
  const ushort* sA0 = H + (size_t)(row0 + arow) * Fm + asub * 8;
  const ushort* sA1 = sA0 + (size_t)64 * Fm;
  const ushort* sB0 = bmat + ((size_t)e * Dm + n0 + arow) * Fm + asub * 8;
  const ushort* sB1 = sB0 + (size_t)64 * Fm;
  char* ldA0 = (char*)As + wid * 1024;
  char* ldA1 = (char*)As + 4096 + wid * 1024;
  char* ldB0 = (char*)Bs + wid * 1024;
  char* ldB1 = (char*)Bs + 4096 + wid * 1024;
  int wr = wid >> 1, wc = wid & 1;
  const ushort* aB = As + ((size_t)(wr * 64 + (lane & 15)) * 32) + (lane >> 4) * 8;
  const ushort* bB = Bs + ((size_t)(wc * 64 + (lane & 15)) * 32) + (lane >> 4) * 8;
  f32x4 acc[4][4] = {};
  for (int kt = 0; kt < Fm / 32; ++kt) {
    GLOAD16(sA0, ldA0);
    GLOAD16(sA1, ldA1);
    GLOAD16(sB0, ldB0);
    GLOAD16(sB1, ldB1);
    sA0 += 32; sA1 += 32; sB0 += 32; sB1 += 32;
    __syncthreads();
    s16x8 av[4], bv[4];
#pragma unroll
    for (int m = 0; m < 4; ++m) av[m] = *(const s16x8*)(aB + m * 512);
#pragma unroll
    for (int n = 0; n < 4; ++n) bv[n] = *(const s16x8*)(bB + n * 512);
#pragma unroll
    for (int m = 0; m < 4; ++m)
#pragma unroll
      for (int n = 0; n < 4; ++n)
        acc[m][n] = __builtin_amdgcn_mfma_f32_16x16x32_bf16(av[m], bv[n], acc[m][n], 0, 0, 0);
    __syncthreads();
  }
  int rb = wr * 64 + ((lane >> 4) << 2);
  int cb = n0 + wc * 64 + (lane & 15);
#pragma unroll
  for (int n = 0; n < 4; ++n) {
    int col = cb + n * 16;
#pragma unroll
    for (int m = 0; m < 4; ++m) {
      int rl = rb + m * 16;
#pragma unroll
      for (int j = 0; j < 4; ++j) {
        int tok = toks[rl + j];
        if (tok >= 0)
          atomicAdd(&out[(size_t)tok * Dm + col], wts[rl + j] * acc[m][n][j]);
      }
    }
  }
}

extern "C" void kernel_launch(void* const* d_in, const int* in_sizes, int n_in,
                              void* d_out, int out_size, void* d_ws, size_t ws_size,
                              hipStream_t stream) {
  const float* x  = (const float*)d_in[0];
  const float* Wr = (const float*)d_in[1];
  const float* br = (const float*)d_in[2];
  const float* W1 = (const float*)d_in[3];
  const float* b1 = (const float*)d_in[4];
  const float* W2 = (const float*)d_in[5];
  const float* b2 = (const float*)d_in[6];
  float* out = (float*)d_out;
  float* probs = out + (size_t)TOKENS * Dm;

  char* ws = (char*)d_ws;
  ushort* Wt   = (ushort*)ws;                          // 67,108,864 B (W1T, then W2T)
  ushort* Hbuf = (ushort*)(ws + 67108864);             // 41,943,040 B
  ushort* xb   = (ushort*)(ws + 109051904);            //  4,194,304 B
  int*   tok_of_row = (int*)(ws + 113246208);          // 20,480 B
  float* w_of_row   = (float*)(ws + 113266688);        // 20,480 B
  int*   e_sel      = (int*)(ws + 113287168);          // 16,384 B
  float* w_sel      = (float*)(ws + 113303552);        // 16,384 B
  int*   meta       = (int*)(ws + 113319936);          // base[8], npad[8], ncnt[8]

  cvt_x<<<2048, 256, 0, stream>>>(x, xb);
  transcvt<<<dim3(Fm / 32, Dm / 32, Em), 256, 0, stream>>>(W1, Wt, Dm, Fm);
  router<<<TOKENS, 256, 0, stream>>>(x, Wr, br, probs, e_sel, w_sel);
  build_lists<<<1, 256, 0, stream>>>(e_sel, w_sel, tok_of_row, w_of_row,
                                     meta, meta + 8, meta + 16);
  out_init<<<TOKENS, 256, 0, stream>>>(e_sel, w_sel, b2, out);
  gemm1<<<dim3(128, 32), 256, 0, stream>>>(xb, Wt, b1, Hbuf, tok_of_row,
                                           meta, meta + 8);
  transcvt<<<dim3(Dm / 32, Fm / 32, Em), 256, 0, stream>>>(W2, Wt, Fm, Dm);
  gemm2<<<dim3(128, 8), 256, 0, stream>>>(Hbuf, Wt, tok_of_row, w_of_row,
                                          meta, meta + 8, out);
}

// Round 2
// 275.698 us; speedup vs baseline: 1.7508x; 1.7508x over previous
//
#include <hip/hip_runtime.h>
#include <hip/hip_bf16.h>
#include <cstdint>

#define TOKENS 2048
#define Dm 1024
#define Fm 4096
#define Em 8

typedef short s16x8 __attribute__((ext_vector_type(8)));
typedef float f32x4 __attribute__((ext_vector_type(4)));

#define GLOAD16(g, l) __builtin_amdgcn_global_load_lds(                     \
    (const __attribute__((address_space(1))) void*)(g),                     \
    (__attribute__((address_space(3))) void*)(l), 16, 0, 0)

__device__ __forceinline__ ushort f2bf(float f) {
  union { float f; uint32_t u; } v; v.f = f;
  uint32_t r = v.u + 0x7fffu + ((v.u >> 16) & 1u);
  return (ushort)(r >> 16);
}

// ------------- transpose+convert: in[e][r][c] f32 -> out[e][c][r] bf16 -------------
__global__ void transcvt(const float* __restrict__ in, ushort* __restrict__ out,
                         int R, int C) {
  __shared__ float tile[32][33];
  int e = blockIdx.z;
  const float* src = in + (size_t)e * R * C;
  ushort* dst = out + (size_t)e * R * C;
  int c0 = blockIdx.x * 32, r0 = blockIdx.y * 32;
  int lr = threadIdx.x >> 5, lc = threadIdx.x & 31; // 8 rows per pass
#pragma unroll
  for (int p = 0; p < 4; ++p) {
    int r = r0 + p * 8 + lr;
    tile[p * 8 + lr][lc] = src[(size_t)r * C + c0 + lc];
  }
  __syncthreads();
#pragma unroll
  for (int p = 0; p < 4; ++p) {
    int c = c0 + p * 8 + lr;
    dst[(size_t)c * R + r0 + lc] = f2bf(tile[lc][p * 8 + lr]);
  }
}

// ---------------- router: logits, top-2, softmax; also emits x in bf16 ----------------
__global__ void router(const float* __restrict__ x, const float* __restrict__ Wr,
                       const float* __restrict__ br, float* __restrict__ probs,
                       int* __restrict__ e_sel, float* __restrict__ w_sel,
                       ushort* __restrict__ xb) {
  int t = blockIdx.x;
  const float4* xr4 = (const float4*)(x + (size_t)t * Dm);
  float4 v = xr4[threadIdx.x];                       // 256 thr * 4 = 1024
  ushort4 o;
  o.x = f2bf(v.x); o.y = f2bf(v.y); o.z = f2bf(v.z); o.w = f2bf(v.w);
  ((ushort4*)(xb + (size_t)t * Dm))[threadIdx.x] = o;

  int d0 = threadIdx.x * 4;
  const float4* wr4 = (const float4*)(Wr + (size_t)d0 * Em);
  float wv[4][8];
#pragma unroll
  for (int r = 0; r < 4; ++r) {
    float4 a = wr4[r * 2], b = wr4[r * 2 + 1];
    wv[r][0] = a.x; wv[r][1] = a.y; wv[r][2] = a.z; wv[r][3] = a.w;
    wv[r][4] = b.x; wv[r][5] = b.y; wv[r][6] = b.z; wv[r][7] = b.w;
  }
  float xs[4] = {v.x, v.y, v.z, v.w};
  float acc[Em];
#pragma unroll
  for (int e = 0; e < Em; ++e)
    acc[e] = xs[0] * wv[0][e] + xs[1] * wv[1][e] + xs[2] * wv[2][e] + xs[3] * wv[3][e];

#pragma unroll
  for (int off = 32; off >= 1; off >>= 1)
#pragma unroll
    for (int e = 0; e < Em; ++e) acc[e] += __shfl_down(acc[e], off);
  __shared__ float red[4][Em];
  int lane = threadIdx.x & 63, wid = threadIdx.x >> 6;
  if (lane == 0)
#pragma unroll
    for (int e = 0; e < Em; ++e) red[wid][e] = acc[e];
  __syncthreads();
  if (threadIdx.x == 0) {
    float lg[Em];
#pragma unroll
    for (int e = 0; e < Em; ++e)
      lg[e] = red[0][e] + red[1][e] + red[2][e] + red[3][e] + br[e];
    int i0 = 0;
    for (int e = 1; e < Em; ++e) if (lg[e] > lg[i0]) i0 = e;
    int i1 = -1;
    for (int e = 0; e < Em; ++e) {
      if (e == i0) continue;
      if (i1 < 0 || lg[e] > lg[i1]) i1 = e;
    }
    float d = lg[i1] - lg[i0];
    float tt = expf(d);
    float inv = 1.f / (1.f + tt);
    float p0 = inv, p1 = tt * inv;
    probs[t * 2] = p0; probs[t * 2 + 1] = p1;
    e_sel[t * 2] = i0; e_sel[t * 2 + 1] = i1;
    w_sel[t * 2] = p0; w_sel[t * 2 + 1] = p1;
  }
}

// ---------------- stable per-expert list build (1 block, 256 thr) ----------------
__global__ void build_lists(const int* __restrict__ e_sel, const float* __restrict__ w_sel,
                            int* __restrict__ tok_of_row, float* __restrict__ w_of_row,
                            int* __restrict__ base, int* __restrict__ npad,
                            int* __restrict__ ncnt) {
  __shared__ int cnt[Em], run[Em], sbase[Em];
  __shared__ int wsum[4][Em];
  int tid = threadIdx.x, lane = tid & 63, wid = tid >> 6;
  if (tid < Em) { cnt[tid] = 0; run[tid] = 0; }
  __syncthreads();
  for (int t = tid; t < TOKENS; t += 256) {
    atomicAdd(&cnt[e_sel[2 * t]], 1);
    atomicAdd(&cnt[e_sel[2 * t + 1]], 1);
  }
  __syncthreads();
  if (tid == 0) {
    int b = 0;
    for (int e = 0; e < Em; ++e) {
      base[e] = b; sbase[e] = b;
      int n = cnt[e]; ncnt[e] = n;
      int p = (n + 127) & ~127;
      npad[e] = p; b += p;
    }
  }
  __syncthreads();
  for (int c = 0; c < TOKENS / 256; ++c) {
    int t = c * 256 + tid;
    int e0 = e_sel[2 * t], e1 = e_sel[2 * t + 1];
    unsigned long long mm[Em];
#pragma unroll
    for (int e = 0; e < Em; ++e) {
      unsigned long long m0 = __ballot(e0 == e);
      unsigned long long m1 = __ballot(e1 == e);
      mm[e] = m0 | m1;
      if (lane == 0) wsum[wid][e] = __popcll(mm[e]);
    }
    __syncthreads();
    unsigned long long below = (1ull << lane) - 1ull;
    {
      int e = e0;
      int p = __popcll(mm[e] & below);
      int pre = 0;
      for (int w = 0; w < wid; ++w) pre += wsum[w][e];
      int row = sbase[e] + run[e] + pre + p;
      tok_of_row[row] = t; w_of_row[row] = w_sel[2 * t];
    }
    {
      int e = e1;
      int p = __popcll(mm[e] & below);
      int pre = 0;
      for (int w = 0; w < wid; ++w) pre += wsum[w][e];
      int row = sbase[e] + run[e] + pre + p;
      tok_of_row[row] = t; w_of_row[row] = w_sel[2 * t + 1];
    }
    __syncthreads();
    if (tid < Em) {
      int s = 0;
      for (int w = 0; w < 4; ++w) s += wsum[w][tid];
      run[tid] += s;
    }
    __syncthreads();
  }
  // pad fill
  for (int e = 0; e < Em; ++e) {
    int n = cnt[e];
    int p = (n + 127) & ~127;
    for (int i = n + tid; i < p; i += 256) {
      tok_of_row[sbase[e] + i] = -1;
      w_of_row[sbase[e] + i] = 0.f;
    }
  }
}

// ---------------- out init: weighted b2 ----------------
__global__ void out_init(const int* __restrict__ e_sel, const float* __restrict__ w_sel,
                         const float* __restrict__ b2, float* __restrict__ out) {
  int t = blockIdx.x;
  int e0 = e_sel[2 * t], e1 = e_sel[2 * t + 1];
  float w0 = w_sel[2 * t], w1 = w_sel[2 * t + 1];
  const float4* p0 = (const float4*)(b2 + (size_t)e0 * Dm);
  const float4* p1 = (const float4*)(b2 + (size_t)e1 * Dm);
  float4* o = (float4*)(out + (size_t)t * Dm);
  for (int i = threadIdx.x; i < Dm / 4; i += 256) {
    float4 a = p0[i], b = p1[i];
    float4 r;
    r.x = w0 * a.x + w1 * b.x; r.y = w0 * a.y + w1 * b.y;
    r.z = w0 * a.z + w1 * b.z; r.w = w0 * a.w + w1 * b.w;
    o[i] = r;
  }
}

// ---------------- GEMM1: H = gelu(Xg @ W1T^T + b1), bf16 out ----------------
// grid: (x = n-tile [32], y = e*16+rt [128])
__global__ __launch_bounds__(256) void gemm1(
    const ushort* __restrict__ xb, const ushort* __restrict__ bmat,
    const float* __restrict__ b1, ushort* __restrict__ H,
    const int* __restrict__ tok_of_row, const int* __restrict__ base,
    const int* __restrict__ npad) {
  int e = blockIdx.y >> 4, rt = blockIdx.y & 15;
  int np = npad[e];
  if (rt * 128 >= np) return;
  int row0 = base[e] + rt * 128;
  int n0 = blockIdx.x * 128;
  __shared__ ushort As[128 * 32];
  __shared__ ushort Bs[128 * 32];
  __shared__ int toks[128];
  int tid = threadIdx.x, lane = tid & 63, wid = tid >> 6;
  if (tid < 128) toks[tid] = tok_of_row[row0 + tid];
  __syncthreads();
  int arow = tid >> 2, asub = tid & 3;
  int t0 = toks[arow];      if (t0 < 0) t0 = 0;
  int t1 = toks[64 + arow]; if (t1 < 0) t1 = 0;
  const ushort* sA0 = xb + (size_t)t0 * Dm + asub * 8;
  const ushort* sA1 = xb + (size_t)t1 * Dm + asub * 8;
  const ushort* sB0 = bmat + ((size_t)e * Fm + n0 + arow) * Dm + asub * 8;
  const ushort* sB1 = sB0 + (size_t)64 * Dm;
  char* ldA0 = (char*)As + wid * 1024;
  char* ldA1 = (char*)As + 4096 + wid * 1024;
  char* ldB0 = (char*)Bs + wid * 1024;
  char* ldB1 = (char*)Bs + 4096 + wid * 1024;
  int wr = wid >> 1, wc = wid & 1;
  const ushort* aB = As + ((size_t)(wr * 64 + (lane & 15)) * 32) + (lane >> 4) * 8;
  const ushort* bB = Bs + ((size_t)(wc * 64 + (lane & 15)) * 32) + (lane >> 4) * 8;
  f32x4 acc[4][4] = {};
  for (int kt = 0; kt < Dm / 32; ++kt) {
    GLOAD16(sA0, ldA0);
    GLOAD16(sA1, ldA1);
    GLOAD16(sB0, ldB0);
    GLOAD16(sB1, ldB1);
    sA0 += 32; sA1 += 32; sB0 += 32; sB1 += 32;
    __syncthreads();
    s16x8 av[4], bv[4];
#pragma unroll
    for (int m = 0; m < 4; ++m) av[m] = *(const s16x8*)(aB + m * 512);
#pragma unroll
    for (int n = 0; n < 4; ++n) bv[n] = *(const s16x8*)(bB + n * 512);
#pragma unroll
    for (int m = 0; m < 4; ++m)
#pragma unroll
      for (int n = 0; n < 4; ++n)
        acc[m][n] = __builtin_amdgcn_mfma_f32_16x16x32_bf16(av[m], bv[n], acc[m][n], 0, 0, 0);
    __syncthreads();
  }
  int rb = wr * 64 + ((lane >> 4) << 2);
  int cb = n0 + wc * 64 + (lane & 15);
#pragma unroll
  for (int n = 0; n < 4; ++n) {
    int col = cb + n * 16;
    float bias = b1[e * Fm + col];
#pragma unroll
    for (int m = 0; m < 4; ++m) {
      int r = row0 + rb + m * 16;
#pragma unroll
      for (int j = 0; j < 4; ++j) {
        float v = acc[m][n][j] + bias;
        float g = 0.5f * v * (1.f + erff(v * 0.70710678118654752f));
        H[(size_t)(r + j) * Fm + col] = f2bf(g);
      }
    }
  }
}

// ---------------- GEMM2: out[tok] += w * (H @ W2T^T) ----------------
// grid: (x = n-tile [8], y = e*16+rt [128], z = k-half [2])
__global__ __launch_bounds__(256) void gemm2(
    const ushort* __restrict__ H, const ushort* __restrict__ bmat,
    const int* __restrict__ tok_of_row, const float* __restrict__ w_of_row,
    const int* __restrict__ base, const int* __restrict__ npad,
    float* __restrict__ out) {
  int e = blockIdx.y >> 4, rt = blockIdx.y & 15;
  int np = npad[e];
  if (rt * 128 >= np) return;
  int row0 = base[e] + rt * 128;
  int n0 = blockIdx.x * 128;
  int k0 = blockIdx.z * (Fm / 2);                 // split-K offset (elements)
  __shared__ ushort As[128 * 32];
  __shared__ ushort Bs[128 * 32];
  __shared__ int toks[128];
  __shared__ float wts[128];
  int tid = threadIdx.x, lane = tid & 63, wid = tid >> 6;
  if (tid < 128) {
    toks[tid] = tok_of_row[row0 + tid];
    wts[tid] = w_of_row[row0 + tid];
  }
  __syncthreads();
  int arow = tid >> 2, asub = tid & 3;
  const ushort* sA0 = H + (size_t)(row0 + arow) * Fm + k0 + asub * 8;
  const ushort* sA1 = sA0 + (size_t)64 * Fm;
  const ushort* sB0 = bmat + ((size_t)e * Dm + n0 + arow) * Fm + k0 + asub * 8;
  const ushort* sB1 = sB0 + (size_t)64 * Fm;
  char* ldA0 = (char*)As + wid * 1024;
  char* ldA1 = (char*)As + 4096 + wid * 1024;
  char* ldB0 = (char*)Bs + wid * 1024;
  char* ldB1 = (char*)Bs + 4096 + wid * 1024;
  int wr = wid >> 1, wc = wid & 1;
  const ushort* aB = As + ((size_t)(wr * 64 + (lane & 15)) * 32) + (lane >> 4) * 8;
  const ushort* bB = Bs + ((size_t)(wc * 64 + (lane & 15)) * 32) + (lane >> 4) * 8;
  f32x4 acc[4][4] = {};
  for (int kt = 0; kt < Fm / 2 / 32; ++kt) {
    GLOAD16(sA0, ldA0);
    GLOAD16(sA1, ldA1);
    GLOAD16(sB0, ldB0);
    GLOAD16(sB1, ldB1);
    sA0 += 32; sA1 += 32; sB0 += 32; sB1 += 32;
    __syncthreads();
    s16x8 av[4], bv[4];
#pragma unroll
    for (int m = 0; m < 4; ++m) av[m] = *(const s16x8*)(aB + m * 512);
#pragma unroll
    for (int n = 0; n < 4; ++n) bv[n] = *(const s16x8*)(bB + n * 512);
#pragma unroll
    for (int m = 0; m < 4; ++m)
#pragma unroll
      for (int n = 0; n < 4; ++n)
        acc[m][n] = __builtin_amdgcn_mfma_f32_16x16x32_bf16(av[m], bv[n], acc[m][n], 0, 0, 0);
    __syncthreads();
  }
  int rb = wr * 64 + ((lane >> 4) << 2);
  int cb = n0 + wc * 64 + (lane & 15);
#pragma unroll
  for (int n = 0; n < 4; ++n) {
    int col = cb + n * 16;
#pragma unroll
    for (int m = 0; m < 4; ++m) {
      int rl = rb + m * 16;
#pragma unroll
      for (int j = 0; j < 4; ++j) {
        int tok = toks[rl + j];
        if (tok >= 0)
          atomicAdd(&out[(size_t)tok * Dm + col], wts[rl + j] * acc[m][n][j]);
      }
    }
  }
}

extern "C" void kernel_launch(void* const* d_in, const int* in_sizes, int n_in,
                              void* d_out, int out_size, void* d_ws, size_t ws_size,
                              hipStream_t stream) {
  const float* x  = (const float*)d_in[0];
  const float* Wr = (const float*)d_in[1];
  const float* br = (const float*)d_in[2];
  const float* W1 = (const float*)d_in[3];
  const float* b1 = (const float*)d_in[4];
  const float* W2 = (const float*)d_in[5];
  const float* b2 = (const float*)d_in[6];
  float* out = (float*)d_out;
  float* probs = out + (size_t)TOKENS * Dm;

  char* ws = (char*)d_ws;
  ushort* Wt   = (ushort*)ws;                          // 67,108,864 B (W1T, then W2T)
  ushort* Hbuf = (ushort*)(ws + 67108864);             // 41,943,040 B
  ushort* xb   = (ushort*)(ws + 109051904);            //  4,194,304 B
  int*   tok_of_row = (int*)(ws + 113246208);          // 20,480 B
  float* w_of_row   = (float*)(ws + 113266688);        // 20,480 B
  int*   e_sel      = (int*)(ws + 113287168);          // 16,384 B
  float* w_sel      = (float*)(ws + 113303552);        // 16,384 B
  int*   meta       = (int*)(ws + 113319936);          // base[8], npad[8], ncnt[8]

  transcvt<<<dim3(Fm / 32, Dm / 32, Em), 256, 0, stream>>>(W1, Wt, Dm, Fm);
  router<<<TOKENS, 256, 0, stream>>>(x, Wr, br, probs, e_sel, w_sel, xb);
  build_lists<<<1, 256, 0, stream>>>(e_sel, w_sel, tok_of_row, w_of_row,
                                     meta, meta + 8, meta + 16);
  out_init<<<TOKENS, 256, 0, stream>>>(e_sel, w_sel, b2, out);
  gemm1<<<dim3(32, 128), 256, 0, stream>>>(xb, Wt, b1, Hbuf, tok_of_row,
                                           meta, meta + 8);
  transcvt<<<dim3(Dm / 32, Fm / 32, Em), 256, 0, stream>>>(W2, Wt, Fm, Dm);
  gemm2<<<dim3(8, 128, 2), 256, 0, stream>>>(Hbuf, Wt, tok_of_row, w_of_row,
                                             meta, meta + 8, out);
}